// Round 6
// baseline (135.534 us; speedup 1.0000x reference)
//
#include <hip/hip_runtime.h>
#include <math.h>

typedef __attribute__((ext_vector_type(8))) short short8;
typedef __attribute__((ext_vector_type(4))) float floatx4;

#define MFMA16(a, b, c) __builtin_amdgcn_mfma_f32_16x16x32_bf16(a, b, c, 0, 0, 0)

extern "C" __device__ float __ocml_native_exp2_f32(float);

// ---- fixed sizes: B=4 L=1024 D=512 H=8 HD=64 HID=256 half-win=16 KK=716 scale=1/8 ----
// q is pre-scaled by 0.125*log2(e) so attn softmax is exp2(s) (raw v_exp_f32).
//
// FRAGMENT-ORDER LAYOUTS: every staged tensor stored as 512-short (1KB) MFMA
// fragment blocks; lane l64's 8 shorts at base + l64*8. All fragment loads are
// contiguous 1KB wave loads (full-line coalesced); gl16 images are exact.

#define FRAG512(row, k) (((size_t)((row) >> 4)) * 8192 + (((k) >> 5) * 512) + \
                         ((((k) >> 3) & 3) * 128) + (((row) & 15) * 8) + ((k) & 7))
#define FRAGQK(row, e)  (((size_t)((row) >> 4)) * 1024 + (((e) >> 5) * 512) + \
                         ((((e) >> 3) & 3) * 128) + (((row) & 15) * 8) + ((e) & 7))

// ---- workspace byte offsets ----
#define OFF_XB    ((size_t)0)          // x bf16 frag [4096][512]
#define OFF_WQKV  ((size_t)4194304)    // Wqkv bf16 frag [1536][512]
#define OFF_WPROJ ((size_t)5767168)    // Wproj bf16 frag [512][512]
#define OFF_Q     ((size_t)6291456)    // q bf16 frag (scale*log2e folded)
#define OFF_K     ((size_t)10485760)   // k bf16 frag
#define OFF_VT    ((size_t)14680064)   // v bf16 frag chunks
#define OFF_AT    ((size_t)18874368)   // attn out bf16 frag [4096][512]
#define OFF_PW    ((size_t)23068672)   // pw fp32 [4][3]
#define OFF_PAR   ((size_t)23069696)   // pool partials fp32 [4][64][512]
#define OFF_W1T   ((size_t)23595008)   // W1^T fp32 [512][256]

__device__ __forceinline__ unsigned short f2bf(float f) {  // RNE (rare paths only)
    unsigned u = __float_as_uint(f);
    return (unsigned short)((u + 0x7fffu + ((u >> 16) & 1u)) >> 16);
}
__device__ __forceinline__ float bf2f(unsigned short s) {
    return __uint_as_float((unsigned)s << 16);
}
// hardware packed f32->bf16 RNE: D[15:0]=bf16(lo), D[31:16]=bf16(hi).
__device__ __forceinline__ unsigned cvt_pk_bf16(float lo, float hi) {
    unsigned r;
    asm("v_cvt_pk_bf16_f32 %0, %1, %2" : "=v"(r) : "v"(lo), "v"(hi));
    return r;
}
// async global->LDS, 16B/lane; LDS dest = wave-uniform base + lane*16 (m104)
__device__ __forceinline__ void gl16(const void* g, void* l) {
    __builtin_amdgcn_global_load_lds(
        (const __attribute__((address_space(1))) unsigned*)g,
        (__attribute__((address_space(3))) unsigned*)l, 16, 0, 0);
}

// ============================================================
// fp32 [16][512] row-major tile -> bf16 fragment-order tile (8192 shorts).
// ============================================================
__device__ __forceinline__ void frag_cvt_tile(const float* __restrict__ src,
                                              unsigned short* __restrict__ dst,
                                              const int t, const float sc)
{
    const int ln = t & 15, quad = (t >> 4) & 3, kh = t >> 6;
    #pragma unroll
    for (int i = 0; i < 4; ++i) {
        const int kb = kh + i * 4;                 // 0..15
        const float* s = src + (size_t)ln * 512 + kb * 32 + quad * 8;
        float4 f0 = *(const float4*)s;
        float4 f1 = *(const float4*)(s + 4);
        unsigned o01 = cvt_pk_bf16(f0.x * sc, f0.y * sc);
        unsigned o23 = cvt_pk_bf16(f0.z * sc, f0.w * sc);
        unsigned o45 = cvt_pk_bf16(f1.x * sc, f1.y * sc);
        unsigned o67 = cvt_pk_bf16(f1.z * sc, f1.w * sc);
        unsigned short* d = dst + kb * 512 + (size_t)(t & 63) * 8;
        *(uint2*)d       = make_uint2(o01, o23);
        *(uint2*)(d + 4) = make_uint2(o45, o67);
    }
}

// ============================================================
// grid 416: [0,256) x->frag + pooling (x reread is L2-hot — one HBM pass);
// [256,384) weights->frag; [384,416) W1 transpose.
// ============================================================
__global__ __launch_bounds__(256)
void cvt_all(const float* __restrict__ x, const float* __restrict__ wqkv,
             const float* __restrict__ wproj, const float* __restrict__ W1,
             unsigned short* __restrict__ xb, unsigned short* __restrict__ oq,
             unsigned short* __restrict__ op, float* __restrict__ partial,
             float* __restrict__ w1t)
{
    const int bid = blockIdx.x, t = threadIdx.x;
    if (bid < 256) {
        const int rt = bid;                        // 16-row tile index
        const float* src = x + (size_t)rt * 16 * 512;
        frag_cvt_tile(src, xb + (size_t)rt * 8192, t, 1.f);
        float s0 = 0.f, s1 = 0.f;
        #pragma unroll 4
        for (int l = 0; l < 16; ++l) {
            s0 += src[(size_t)l * 512 + t];
            s1 += src[(size_t)l * 512 + t + 256];
        }
        partial[(size_t)rt * 512 + t] = s0;
        partial[(size_t)rt * 512 + t + 256] = s1;
    } else if (bid < 384) {
        const int tile = bid - 256;                // 0..127
        if (tile < 96)
            frag_cvt_tile(wqkv + (size_t)tile * 16 * 512, oq + (size_t)tile * 8192, t, 1.f);
        else
            frag_cvt_tile(wproj + (size_t)(tile - 96) * 16 * 512,
                          op + (size_t)(tile - 96) * 8192, t, 1.f);
    } else {
        // ---- W1 [256][512] -> W1T [512][256], 64x64 tile per block ----
        __shared__ float tl[64][65];
        const int tile = bid - 384;                // 0..31
        const int tr = tile >> 3, tc = tile & 7;
        const int lr = t >> 6, lc = t & 63;
        #pragma unroll
        for (int p = 0; p < 16; ++p) {
            const int r = p * 4 + lr;
            tl[r][lc] = W1[(size_t)(tr * 64 + r) * 512 + tc * 64 + lc];
        }
        __syncthreads();
        #pragma unroll
        for (int p = 0; p < 16; ++p) {
            const int d = p * 4 + lr;
            w1t[(size_t)(tc * 64 + d) * 256 + tr * 64 + lc] = tl[lc][d];
        }
    }
}

// ============================================================
// QKV GEMM + selector fold — v3: 128x128 tiles + XCD swizzle (round-3 proven)
// + gl16 LDS STAGING (T3 minimum 2-phase; m97 ladder's biggest step):
//  - v2 streamed fragments from L2 with only a 2-k-step register prefetch:
//    8 global loads (L2-hit ~200cyc) vs ~80cyc MFMA per k-step at 1-2
//    waves/SIMD -> load-latency-bound.
//  - v3: per BK=32 k-block, stage A(128x32)+B(128x32) = 16KB into LDS via 16
//    gl16 (4/wave), double-buffered; compute reads 8 ds_read_b128 (linear,
//    conflict-free) + 16 MFMA. One __syncthreads per step (compiler emits the
//    vmcnt/lgkm drain). k-accumulation order unchanged -> bit-identical C.
//  - epilogue + selector tail alias the staging LDS (union, 36 KB).
// grid (12, 33): by==32/bx<4 is the selector tail.
// ============================================================
__global__ __launch_bounds__(256)
void gemm_qkv_sel(const unsigned short* __restrict__ xb, const unsigned short* __restrict__ wb,
                  unsigned short* __restrict__ qo, unsigned short* __restrict__ ko,
                  unsigned short* __restrict__ vo,
                  const float* __restrict__ partial, const float* __restrict__ w1t,
                  const float* __restrict__ b1, const float* __restrict__ W2,
                  const float* __restrict__ b2, const float* __restrict__ ltau,
                  float* __restrict__ pwout)
{
    __shared__ __align__(16) union SmT {
        unsigned short stage[2][8192];   // 2 x (A 8KB | B 8KB) k-block staging
        unsigned short tile[4][4608];    // epilogue transpose / selector scratch
    } sm;
    const int t = threadIdx.x;
    const int w = t >> 6, l64 = t & 63;

    if (blockIdx.y == 32) {
        if (blockIdx.x >= 4) return;
        const int b = blockIdx.x;
        float* pooled = (float*)&sm.tile[0][0];  // 512 f
        float* hpart  = pooled + 512;            // 4 x 256 f
        float* h1s    = hpart + 1024;            // 256 f
        float* lg     = h1s + 256;               // 3 f
        #pragma unroll
        for (int c = 0; c < 2; ++c) {
            const int col = t + c * 256;
            float s = 0.f;
            for (int p = 0; p < 64; ++p) s += partial[((size_t)b * 64 + p) * 512 + col];
            pooled[col] = s * (1.f / 1024.f);
        }
        __syncthreads();
        {
            // h1 partial: wave w covers pooled-d in [w*128, (w+1)*128)
            float4 acc = make_float4(0.f, 0.f, 0.f, 0.f);
            const float* wt = w1t + (size_t)w * 128 * 256 + l64 * 4;
            for (int d = 0; d < 128; ++d) {
                const float pv = pooled[w * 128 + d];
                float4 wv = *(const float4*)(wt + (size_t)d * 256);
                acc.x += pv * wv.x; acc.y += pv * wv.y;
                acc.z += pv * wv.z; acc.w += pv * wv.w;
            }
            *(float4*)&hpart[w * 256 + l64 * 4] = acc;
        }
        __syncthreads();
        h1s[t] = fmaxf(hpart[t] + hpart[256 + t] + hpart[512 + t] + hpart[768 + t] + b1[t], 0.f);
        __syncthreads();
        if (t < 3) {
            float s = b2[t];
            const float* w2 = W2 + t * 256;
            for (int i = 0; i < 256; ++i) s += w2[i] * h1s[i];
            float tauv = fminf(fmaxf(expf(ltau[0]), 1e-4f), 10.f);
            lg[t] = s / tauv;
        }
        __syncthreads();
        if (t == 0) {
            float m = fmaxf(lg[0], fmaxf(lg[1], lg[2]));
            float e0 = expf(lg[0] - m), e1 = expf(lg[1] - m), e2 = expf(lg[2] - m);
            float inv = 1.f / (e0 + e1 + e2);
            pwout[b * 3 + 0] = e0 * inv;
            pwout[b * 3 + 1] = e1 * inv;
            pwout[b * 3 + 2] = e2 * inv;
        }
        return;
    }

    // ---- GEMM path: XCD-chunked bijective swizzle (384 = 48*8 blocks) ----
    const int wg = blockIdx.y * 12 + blockIdx.x;       // dispatch order, x fastest
    const int sw_id = (wg & 7) * 48 + (wg >> 3);       // XCD k gets logical [k*48, k*48+48)
    const int bx = sw_id % 12, by = sw_id / 12;

    const int ln = l64 & 15, quad = l64 >> 4;
    const int mq = w >> 1, nq = w & 1;                 // wave quadrant (2m x 2n)
    const int m0  = (by << 7) + (mq << 6);             // wave's 64m x 64n
    const int nb0 = (bx << 7) + (nq << 6);

    // block-level fragment bases: A row-groups 0..7 (128 rows), B groups 0..7
    const unsigned short* Ag = xb + ((size_t)(by << 3)) * 8192;
    const unsigned short* Bg = wb + ((size_t)(bx << 3)) * 8192;

    floatx4 acc[4][4];
    #pragma unroll
    for (int i = 0; i < 4; ++i)
        #pragma unroll
        for (int j = 0; j < 4; ++j) acc[i][j] = (floatx4){0.f, 0.f, 0.f, 0.f};

    // prologue: stage k-block 0 (16 x 1KB segments; wave w moves segs w*4..w*4+3)
    {
        #pragma unroll
        for (int c = 0; c < 4; ++c) {
            const int seg = w * 4 + c;
            const unsigned short* src = (seg < 8)
                ? Ag + (size_t)seg * 8192 + l64 * 8
                : Bg + (size_t)(seg - 8) * 8192 + l64 * 8;
            gl16(src, (char*)sm.stage[0] + seg * 1024);
        }
    }
    __syncthreads();   // k-block 0 landed

    for (int s = 0; s < 16; ++s) {
        const int cur = s & 1;
        if (s < 15) {
            #pragma unroll
            for (int c = 0; c < 4; ++c) {
                const int seg = w * 4 + c;
                const unsigned short* src = (seg < 8)
                    ? Ag + (size_t)seg * 8192 + (s + 1) * 512 + l64 * 8
                    : Bg + (size_t)(seg - 8) * 8192 + (s + 1) * 512 + l64 * 8;
                gl16(src, (char*)sm.stage[cur ^ 1] + seg * 1024);
            }
        }
        const unsigned short* As = sm.stage[cur] + (mq * 4) * 512 + l64 * 8;
        const unsigned short* Bs = sm.stage[cur] + 4096 + (nq * 4) * 512 + l64 * 8;
        short8 av[4], bv[4];
        #pragma unroll
        for (int i = 0; i < 4; ++i) {
            av[i] = *(const short8*)(As + i * 512);
            bv[i] = *(const short8*)(Bs + i * 512);
        }
        #pragma unroll
        for (int i = 0; i < 4; ++i)
            #pragma unroll
            for (int j = 0; j < 4; ++j)
                acc[i][j] = MFMA16(av[i], bv[j], acc[i][j]);
        __syncthreads();   // drains next-block gl16; frees buf[cur] for s+2
    }

    unsigned short* tw = &sm.tile[w][0];
    const int which = nb0 >> 9;                  // 0=q 1=k 2=v
    const int hh = (nb0 >> 6) & 7;
    const int g = (m0 >> 10) * 8 + hh;
    const int lrow0 = m0 & 1023;

    if (which == 2) {
        // reg dimension is contiguous in tw -> pack pairs, store uint2 (b64)
        #pragma unroll
        for (int j = 0; j < 4; ++j)
            #pragma unroll
            for (int i = 0; i < 4; ++i) {
                unsigned u01 = cvt_pk_bf16(acc[i][j][0], acc[i][j][1]);
                unsigned u23 = cvt_pk_bf16(acc[i][j][2], acc[i][j][3]);
                *(uint2*)&tw[(j * 16 + ln) * 72 + i * 16 + quad * 4] = make_uint2(u01, u23);
            }
        const int chunk = lrow0 >> 7;
        const int ks0 = (lrow0 & 127) >> 5;
        unsigned short* dst = vo + (size_t)g * 65536 + (size_t)chunk * 8192;
        #pragma unroll
        for (int et = 0; et < 4; ++et)
            #pragma unroll
            for (int ksl = 0; ksl < 2; ++ksl) {
                const unsigned short* srcp = &tw[(et * 16 + ln) * 72 + ksl * 32 + quad * 8];
                *(short8*)(dst + (et * 4 + ks0 + ksl) * 512 + l64 * 8) = *(const short8*)srcp;
            }
    } else {
        // fold q scale AND log2e (softmax becomes exp2): monotone, radix-safe
        const float sc = (which == 0) ? 0.180336880f : 1.f;   // 0.125 * log2(e)
        #pragma unroll
        for (int j = 0; j < 4; ++j)
            #pragma unroll
            for (int i = 0; i < 4; ++i) {
                unsigned u01 = cvt_pk_bf16(acc[i][j][0] * sc, acc[i][j][1] * sc);
                unsigned u23 = cvt_pk_bf16(acc[i][j][2] * sc, acc[i][j][3] * sc);
                const int rb = (i * 16 + quad * 4) * 72 + j * 16 + ln;
                tw[rb]           = (unsigned short)u01;
                tw[rb + 72]      = (unsigned short)(u01 >> 16);
                tw[rb + 144]     = (unsigned short)u23;
                tw[rb + 216]     = (unsigned short)(u23 >> 16);
            }
        unsigned short* dst = (which == 0 ? qo : ko) + (size_t)g * 65536;
        #pragma unroll
        for (int rt = 0; rt < 4; ++rt)
            #pragma unroll
            for (int eh = 0; eh < 2; ++eh) {
                const unsigned short* srcp = &tw[(rt * 16 + ln) * 72 + eh * 32 + quad * 8];
                *(short8*)(dst + ((size_t)((lrow0 >> 4) + rt)) * 1024 + eh * 512 + l64 * 8) =
                    *(const short8*)srcp;
            }
    }
}

// ============================================================
// Proj GEMM — v2: 64m x 128n per 4-wave block, wave quadrants 32m x 64n;
// grid 256 blocks with XCD-chunked bijective swizzle.
// ============================================================
__global__ __launch_bounds__(256)
void gemm_proj(const unsigned short* __restrict__ ab, const unsigned short* __restrict__ wb,
               const float* __restrict__ bias, float* __restrict__ out)
{
    const int t = threadIdx.x;
    const int w = t >> 6, l64 = t & 63;
    const int ln = l64 & 15, quad = l64 >> 4;

    // grid (4,64) = 256 blocks; swizzle: XCD k gets logical blocks [k*32,(k+1)*32)
    const int wg = blockIdx.y * 4 + blockIdx.x;
    const int sw_id = (wg & 7) * 32 + (wg >> 3);
    const int n0 = ((sw_id & 3) << 7) + ((w & 1) << 6);    // wave: 32m x 64n
    const int m0 = ((sw_id >> 2) << 6) + ((w >> 1) << 5);

    const unsigned short* Abase = ab + ((size_t)(m0 >> 4)) * 8192 + l64 * 8;
    const unsigned short* Bbase = wb + ((size_t)(n0 >> 4)) * 8192 + l64 * 8;

    floatx4 acc[2][4];
    #pragma unroll
    for (int i = 0; i < 2; ++i)
        #pragma unroll
        for (int j = 0; j < 4; ++j) acc[i][j] = (floatx4){0.f, 0.f, 0.f, 0.f};

    short8 a0[2], b0[4], a1[2], b1v[4];
    #pragma unroll
    for (int i = 0; i < 2; ++i) a0[i] = *(const short8*)(Abase + (size_t)i * 8192);
    #pragma unroll
    for (int j = 0; j < 4; ++j) b0[j] = *(const short8*)(Bbase + (size_t)j * 8192);
    for (int s = 0; s < 16; s += 2) {
        #pragma unroll
        for (int i = 0; i < 2; ++i) a1[i]  = *(const short8*)(Abase + (size_t)i * 8192 + (s + 1) * 512);
        #pragma unroll
        for (int j = 0; j < 4; ++j) b1v[j] = *(const short8*)(Bbase + (size_t)j * 8192 + (s + 1) * 512);
        #pragma unroll
        for (int i = 0; i < 2; ++i)
            #pragma unroll
            for (int j = 0; j < 4; ++j)
                acc[i][j] = MFMA16(a0[i], b0[j], acc[i][j]);
        if (s + 2 < 16) {
            #pragma unroll
            for (int i = 0; i < 2; ++i) a0[i] = *(const short8*)(Abase + (size_t)i * 8192 + (s + 2) * 512);
            #pragma unroll
            for (int j = 0; j < 4; ++j) b0[j] = *(const short8*)(Bbase + (size_t)j * 8192 + (s + 2) * 512);
        }
        #pragma unroll
        for (int i = 0; i < 2; ++i)
            #pragma unroll
            for (int j = 0; j < 4; ++j)
                acc[i][j] = MFMA16(a1[i], b1v[j], acc[i][j]);
    }
    #pragma unroll
    for (int j = 0; j < 4; ++j) {
        const float bv = bias[n0 + j * 16 + ln];
        #pragma unroll
        for (int i = 0; i < 2; ++i)
            #pragma unroll
            for (int reg = 0; reg < 4; ++reg)
                out[(size_t)(m0 + i * 16 + quad * 4 + reg) * 512 + n0 + j * 16 + ln] =
                    acc[i][j][reg] + bv;
    }
}

// ============================================================
// Flash attention v6: K dbuf + mid-chunk V drain; exp2 softmax; hw pk cvt;
// s_setprio(1) around MFMA clusters.
// block = 64 Q-rows (wave = 16), grid 512, 2 blocks/CU (LDS 70.9 KB).
// ============================================================
__global__ __launch_bounds__(256)
void attn_flash(const unsigned short* __restrict__ qm, const unsigned short* __restrict__ km,
                const unsigned short* __restrict__ vm, const int* __restrict__ mask,
                const float* __restrict__ pw, const float* __restrict__ sw,
                const float* __restrict__ sb, unsigned short* __restrict__ aout)
{
    __shared__ int mk[1024];
    __shared__ __align__(16) unsigned short Ks[2][8192];   // K chunk double buffer (32 KB)
    __shared__ __align__(16) unsigned short Vs[8192];      // V chunk single buffer (16 KB)
    __shared__ __align__(16) unsigned short Pws[4][2176];  // per-wave P staging [16][136]
    __shared__ unsigned kths[4][16];

    const int t = threadIdx.x;
    const int w = t >> 6, l64 = t & 63;
    const int ln = l64 & 15, quad = l64 >> 4;
    const int g = blockIdx.x & 31;
    const int rg = blockIdx.x >> 5;
    const int b = g >> 3, h = g & 7;
    const int i0 = rg * 64 + w * 16;

    const unsigned short* qg = qm + (size_t)g * 65536;
    const unsigned short* kg = km + (size_t)g * 65536;
    const unsigned short* vg = vm + (size_t)g * 65536;

    *(int4*)&mk[t * 4] = *(const int4*)(mask + b * 1024 + t * 4);

    const float pw0 = pw[b * 3 + 0], pw1 = pw[b * 3 + 1], pw2 = pw[b * 3 + 2];
    const bool a00 = pw1 > 0.05f;
    const bool a10 = (pw0 * 1.0f + pw1) > 0.05f;
    const bool a01 = (pw1 + pw2) > 0.05f;
    const bool a11 = ((pw0 * 1.0f + pw1) + pw2) > 0.05f;
    const bool need_sparse = (!a00 && a01) || (!a10 && a11);
    const bool flat_ok = (!need_sparse) && a00 && a10;  // allowed==true iff mk!=0, exactly
    const float w_h = sw[h], b_h = sb[h];

    // ---- prefetch K chunk 0 -> Ks[0]; drained at the pre-loop barrier ----
    #pragma unroll
    for (int c = 0; c < 4; ++c) {
        const int bi = w * 4 + c;
        gl16(kg + bi * 512 + l64 * 8, (char*)Ks[0] + bi * 1024);
    }

    // ---- rare path: exact per-row kth (k=716), bitwise radix select.
    //      scratch aliases Ks[1] (dead until the pre-loop barrier).
    unsigned kth_r[4] = {0u, 0u, 0u, 0u};
    if (need_sparse) {
        unsigned* ub = (unsigned*)((char*)Ks + 16384 + w * 4096);
        for (int r = 0; r < 16; ++r) {
            for (int c = 0; c < 16; ++c) {
                const int col = c * 64 + l64;
                float s = 0.f;
                for (int e = 0; e < 64; ++e)
                    s += bf2f(qg[FRAGQK(i0 + r, e)]) * bf2f(kg[FRAGQK(col, e)]);
                unsigned uu = __float_as_uint(s * w_h + b_h);
                ub[col] = (uu & 0x80000000u) ? ~uu : (uu | 0x80000000u);
            }
            unsigned u[16];
            #pragma unroll
            for (int c = 0; c < 16; ++c) u[c] = ub[l64 + c * 64];
            unsigned act = 0xFFFFu, p = 0u;
            int kk = 716;
            for (int bit = 31; bit >= 0; --bit) {
                unsigned ones = 0u;
                #pragma unroll
                for (int c = 0; c < 16; ++c)
                    if (((act >> c) & 1u) && ((u[c] >> bit) & 1u)) ones |= (1u << c);
                int c1 = __popc(ones);
                for (int off = 32; off; off >>= 1) c1 += __shfl_xor(c1, off);
                if (kk <= c1) { p |= (1u << bit); act &= ones; }
                else          { kk -= c1; act &= ~ones; }
            }
            if (l64 == 0) kths[w][r] = p;
        }
        #pragma unroll
        for (int reg = 0; reg < 4; ++reg) kth_r[reg] = kths[w][quad * 4 + reg];
    }

    const short8 aq0 = *(const short8*)(qg + ((size_t)(i0 >> 4)) * 1024 + l64 * 8);
    const short8 aq1 = *(const short8*)(qg + ((size_t)(i0 >> 4)) * 1024 + 512 + l64 * 8);

    __syncthreads();   // K(0) landed; mk visible; radix scratch in Ks[1] dead

    float l_acc[4] = {0.f, 0.f, 0.f, 0.f};     // per-lane partial row sums
    floatx4 accv[4];
    #pragma unroll
    for (int et = 0; et < 4; ++et) accv[et] = (floatx4){0.f, 0.f, 0.f, 0.f};
    unsigned short* Pw = &Pws[w][0];

    for (int jc = 0; jc < 8; ++jc) {
        const int j0 = jc << 7;
        const int cur = jc & 1;
        const unsigned short* Kc = &Ks[cur][0];
        // ---- stage V(jc) now (consumed after the MID barrier);
        //      prefetch K(jc+1) into the spare K buffer (consumed next chunk) ----
        {
            const unsigned short* vc = vg + (size_t)jc * 8192;
            #pragma unroll
            for (int c = 0; c < 4; ++c) {
                const int bi = w * 4 + c;
                gl16(vc + bi * 512 + l64 * 8, (char*)Vs + bi * 1024);
            }
            if (jc < 7) {
                const unsigned short* kc = kg + (size_t)(jc + 1) * 8192;
                #pragma unroll
                for (int c = 0; c < 4; ++c) {
                    const int bi = w * 4 + c;
                    gl16(kc + bi * 512 + l64 * 8, (char*)Ks[cur ^ 1] + bi * 1024);
                }
            }
        }
        const bool mall = __all((mk[j0 + l64] != 0) && (mk[j0 + 64 + l64] != 0));
        const bool fast = flat_ok && mall;

        // ---- QK^T from LDS K (K(jc) landed at the previous barrier) ----
        floatx4 sfr[8];
        __builtin_amdgcn_s_setprio(1);
        #pragma unroll
        for (int nt = 0; nt < 8; ++nt) {
            const short8 kb0 = *(const short8*)(Kc + nt * 1024 + l64 * 8);
            const short8 kb1 = *(const short8*)(Kc + nt * 1024 + 512 + l64 * 8);
            floatx4 z = (floatx4){0.f, 0.f, 0.f, 0.f};
            z = MFMA16(aq0, kb0, z);
            z = MFMA16(aq1, kb1, z);
            sfr[nt] = z;
        }
        __builtin_amdgcn_s_setprio(0);

        // ---- masking (no row-max needed: m fixed at 0) ----
        if (!fast) {
            #pragma unroll
            for (int nt = 0; nt < 8; ++nt) {
                const int j = j0 + nt * 16 + ln;
                const bool mk0 = (mk[j] == 0);
                #pragma unroll
                for (int reg = 0; reg < 4; ++reg) {
                    const int i = i0 + quad * 4 + reg;
                    const float s = sfr[nt][reg];
                    const bool loc = (j >= i - 16) && (j <= i + 16);
                    bool sm = false;
                    if (need_sparse) {
                        unsigned uu = __float_as_uint(s * w_h + b_h);
                        unsigned key = (uu & 0x80000000u) ? ~uu : (uu | 0x80000000u);
                        sm = key >= kth_r[reg];
                    }
                    bool allowed = loc ? (sm ? a11 : a10) : (sm ? a01 : a00);
                    if (mk0) allowed = false;
                    sfr[nt][reg] = allowed ? s : -1e9f;
                }
            }
        }
        // ---- P = exp2(s) -> bf16 (hw pk cvt) -> wave-private LDS ----
        #pragma unroll
        for (int nt = 0; nt < 8; ++nt) {
            const float p0 = __ocml_native_exp2_f32(sfr[nt][0]);  // masked -> +0 exactly
            const float p1 = __ocml_native_exp2_f32(sfr[nt][1]);
            const float p2 = __ocml_native_exp2_f32(sfr[nt][2]);
            const float p3 = __ocml_native_exp2_f32(sfr[nt][3]);
            l_acc[0] += p0; l_acc[1] += p1; l_acc[2] += p2; l_acc[3] += p3;
            const unsigned u01 = cvt_pk_bf16(p0, p1);
            const unsigned u23 = cvt_pk_bf16(p2, p3);
            const int col = nt * 16 + ln;
            Pw[(quad * 4 + 0) * 136 + col] = (unsigned short)u01;
            Pw[(quad * 4 + 1) * 136 + col] = (unsigned short)(u01 >> 16);
            Pw[(quad * 4 + 2) * 136 + col] = (unsigned short)u23;
            Pw[(quad * 4 + 3) * 136 + col] = (unsigned short)(u23 >> 16);
        }
        short8 pa[4];
        #pragma unroll
        for (int ks = 0; ks < 4; ++ks)
            pa[ks] = *(const short8*)&Pw[ln * 136 + ks * 32 + quad * 8];
        __syncthreads();   // MID: drains V(jc)+K(jc+1) under the QK^T/exp shadow
        // ---- PV from LDS V (no alpha rescale: m is constant) ----
        __builtin_amdgcn_s_setprio(1);
        #pragma unroll
        for (int et = 0; et < 4; ++et) {
            floatx4 a = accv[et];
            #pragma unroll
            for (int ks = 0; ks < 4; ++ks) {
                const short8 bv = *(const short8*)(Vs + (et * 4 + ks) * 512 + l64 * 8);
                a = MFMA16(pa[ks], bv, a);
            }
            accv[et] = a;
        }
        __builtin_amdgcn_s_setprio(0);
        __syncthreads();   // END: Vs consumed -> next chunk may restage it
    }

    // ---- single deferred row-sum reduce (16 shuffles total) ----
    #pragma unroll
    for (int reg = 0; reg < 4; ++reg) {
        float v = l_acc[reg];
        v += __shfl_xor(v, 1);
        v += __shfl_xor(v, 2);
        v += __shfl_xor(v, 4);
        v += __shfl_xor(v, 8);
        l_acc[reg] = v;
    }

    // ---- writeback: normalize (or exact v[0] fallback when l==0).
    //      fp32 staging aliases the now-dead Ks buffer ([16][68] per wave). ----
    float* PO_w = (float*)((char*)Ks + w * 4352);
    #pragma unroll
    for (int et = 0; et < 4; ++et)
        #pragma unroll
        for (int reg = 0; reg < 4; ++reg) {
            float val;
            if (l_acc[reg] == 0.f)
                val = bf2f(vg[et * 2048 + ln * 8]);   // v[0][e], e = et*16+ln
            else
                val = accv[et][reg] / l_acc[reg];
            PO_w[(quad * 4 + reg) * 68 + et * 16 + ln] = val;
        }
    #pragma unroll
    for (int rr = 0; rr < 4; ++rr) {
        const int r = (l64 >> 4) * 4 + rr;
        const int cb = (l64 & 15) * 4;
        float4 ov = *(const float4*)&PO_w[r * 68 + cb];
        const unsigned uxy = cvt_pk_bf16(ov.x, ov.y);
        const unsigned uzw = cvt_pk_bf16(ov.z, ov.w);
        const int row_g = b * 1024 + i0 + r;
        const int col = h * 64 + cb;
        *(uint2*)&aout[FRAG512(row_g, col)] = make_uint2(uxy, uzw);
    }
}

// ============================================================
extern "C" void kernel_launch(void* const* d_in, const int* in_sizes, int n_in,
                              void* d_out, int out_size, void* d_ws, size_t ws_size,
                              hipStream_t stream) {
    const float* x     = (const float*)d_in[0];
    const int*   mask  = (const int*)d_in[1];
    const float* Wqkv  = (const float*)d_in[2];
    const float* Wproj = (const float*)d_in[3];
    const float* bproj = (const float*)d_in[4];
    const float* Wsel1 = (const float*)d_in[5];
    const float* bsel1 = (const float*)d_in[6];
    const float* Wsel2 = (const float*)d_in[7];
    const float* bsel2 = (const float*)d_in[8];
    const float* ltau  = (const float*)d_in[9];
    const float* sw    = (const float*)d_in[10];
    const float* sb    = (const float*)d_in[11];
    char* ws = (char*)d_ws;
    unsigned short* xb     = (unsigned short*)(ws + OFF_XB);
    unsigned short* wqkvb  = (unsigned short*)(ws + OFF_WQKV);
    unsigned short* wprojb = (unsigned short*)(ws + OFF_WPROJ);
    unsigned short* q      = (unsigned short*)(ws + OFF_Q);
    unsigned short* k      = (unsigned short*)(ws + OFF_K);
    unsigned short* v      = (unsigned short*)(ws + OFF_VT);
    unsigned short* attnb  = (unsigned short*)(ws + OFF_AT);
    float* pw  = (float*)(ws + OFF_PW);
    float* par = (float*)(ws + OFF_PAR);
    float* w1t = (float*)(ws + OFF_W1T);
    float* out = (float*)d_out;
    (void)in_sizes; (void)n_in; (void)out_size; (void)ws_size;

    cvt_all<<<416, 256, 0, stream>>>(x, Wqkv, Wproj, Wsel1, xb, wqkvb, wprojb, par, w1t);
    gemm_qkv_sel<<<dim3(12, 33), 256, 0, stream>>>(xb, wqkvb, q, k, v,
                                                   par, w1t, bsel1, Wsel2, bsel2, ltau, pw);
    attn_flash<<<512, 256, 0, stream>>>(q, k, v, mask, pw, sw, sb, attnb);
    gemm_proj<<<dim3(4, 64), 256, 0, stream>>>(attnb, wprojb, bproj, out);
}

// Round 7
// 133.560 us; speedup vs baseline: 1.0148x; 1.0148x over previous
//
#include <hip/hip_runtime.h>
#include <math.h>

typedef __attribute__((ext_vector_type(8))) short short8;
typedef __attribute__((ext_vector_type(4))) float floatx4;

#define MFMA16(a, b, c) __builtin_amdgcn_mfma_f32_16x16x32_bf16(a, b, c, 0, 0, 0)

extern "C" __device__ float __ocml_native_exp2_f32(float);

// ---- fixed sizes: B=4 L=1024 D=512 H=8 HD=64 HID=256 half-win=16 KK=716 scale=1/8 ----
// q is pre-scaled by 0.125*log2(e) so attn softmax is exp2(s) (raw v_exp_f32).
//
// FRAGMENT-ORDER LAYOUTS: every staged tensor stored as 512-short (1KB) MFMA
// fragment blocks; lane l64's 8 shorts at base + l64*8. All fragment loads are
// contiguous 1KB wave loads (full-line coalesced); gl16 images are exact.
//
// ROUND-6 LESSON (measured twice): these kernels are L2-resident + latency-
// covered; pipeline-depth techniques (gl16 staging, deeper dbuf) are null-to-
// negative here. v2 register-streamed qkv (round 4, 134.18us) is the proven
// best — restored verbatim.

#define FRAG512(row, k) (((size_t)((row) >> 4)) * 8192 + (((k) >> 5) * 512) + \
                         ((((k) >> 3) & 3) * 128) + (((row) & 15) * 8) + ((k) & 7))
#define FRAGQK(row, e)  (((size_t)((row) >> 4)) * 1024 + (((e) >> 5) * 512) + \
                         ((((e) >> 3) & 3) * 128) + (((row) & 15) * 8) + ((e) & 7))

// ---- workspace byte offsets ----
#define OFF_XB    ((size_t)0)          // x bf16 frag [4096][512]
#define OFF_WQKV  ((size_t)4194304)    // Wqkv bf16 frag [1536][512]
#define OFF_WPROJ ((size_t)5767168)    // Wproj bf16 frag [512][512]
#define OFF_Q     ((size_t)6291456)    // q bf16 frag (scale*log2e folded)
#define OFF_K     ((size_t)10485760)   // k bf16 frag
#define OFF_VT    ((size_t)14680064)   // v bf16 frag chunks
#define OFF_AT    ((size_t)18874368)   // attn out bf16 frag [4096][512]
#define OFF_PW    ((size_t)23068672)   // pw fp32 [4][3]
#define OFF_PAR   ((size_t)23069696)   // pool partials fp32 [4][64][512]
#define OFF_W1T   ((size_t)23595008)   // W1^T fp32 [512][256]

__device__ __forceinline__ unsigned short f2bf(float f) {  // RNE (rare paths only)
    unsigned u = __float_as_uint(f);
    return (unsigned short)((u + 0x7fffu + ((u >> 16) & 1u)) >> 16);
}
__device__ __forceinline__ float bf2f(unsigned short s) {
    return __uint_as_float((unsigned)s << 16);
}
// hardware packed f32->bf16 RNE: D[15:0]=bf16(lo), D[31:16]=bf16(hi).
__device__ __forceinline__ unsigned cvt_pk_bf16(float lo, float hi) {
    unsigned r;
    asm("v_cvt_pk_bf16_f32 %0, %1, %2" : "=v"(r) : "v"(lo), "v"(hi));
    return r;
}
// async global->LDS, 16B/lane; LDS dest = wave-uniform base + lane*16 (m104)
__device__ __forceinline__ void gl16(const void* g, void* l) {
    __builtin_amdgcn_global_load_lds(
        (const __attribute__((address_space(1))) unsigned*)g,
        (__attribute__((address_space(3))) unsigned*)l, 16, 0, 0);
}

// ============================================================
// fp32 [16][512] row-major tile -> bf16 fragment-order tile (8192 shorts).
// ============================================================
__device__ __forceinline__ void frag_cvt_tile(const float* __restrict__ src,
                                              unsigned short* __restrict__ dst,
                                              const int t, const float sc)
{
    const int ln = t & 15, quad = (t >> 4) & 3, kh = t >> 6;
    #pragma unroll
    for (int i = 0; i < 4; ++i) {
        const int kb = kh + i * 4;                 // 0..15
        const float* s = src + (size_t)ln * 512 + kb * 32 + quad * 8;
        float4 f0 = *(const float4*)s;
        float4 f1 = *(const float4*)(s + 4);
        unsigned o01 = cvt_pk_bf16(f0.x * sc, f0.y * sc);
        unsigned o23 = cvt_pk_bf16(f0.z * sc, f0.w * sc);
        unsigned o45 = cvt_pk_bf16(f1.x * sc, f1.y * sc);
        unsigned o67 = cvt_pk_bf16(f1.z * sc, f1.w * sc);
        unsigned short* d = dst + kb * 512 + (size_t)(t & 63) * 8;
        *(uint2*)d       = make_uint2(o01, o23);
        *(uint2*)(d + 4) = make_uint2(o45, o67);
    }
}

// ============================================================
// grid 416: [0,256) x->frag + pooling (x reread is L2-hot — one HBM pass);
// [256,384) weights->frag; [384,416) W1 transpose.
// ============================================================
__global__ __launch_bounds__(256)
void cvt_all(const float* __restrict__ x, const float* __restrict__ wqkv,
             const float* __restrict__ wproj, const float* __restrict__ W1,
             unsigned short* __restrict__ xb, unsigned short* __restrict__ oq,
             unsigned short* __restrict__ op, float* __restrict__ partial,
             float* __restrict__ w1t)
{
    const int bid = blockIdx.x, t = threadIdx.x;
    if (bid < 256) {
        const int rt = bid;                        // 16-row tile index
        const float* src = x + (size_t)rt * 16 * 512;
        frag_cvt_tile(src, xb + (size_t)rt * 8192, t, 1.f);
        float s0 = 0.f, s1 = 0.f;
        #pragma unroll 4
        for (int l = 0; l < 16; ++l) {
            s0 += src[(size_t)l * 512 + t];
            s1 += src[(size_t)l * 512 + t + 256];
        }
        partial[(size_t)rt * 512 + t] = s0;
        partial[(size_t)rt * 512 + t + 256] = s1;
    } else if (bid < 384) {
        const int tile = bid - 256;                // 0..127
        if (tile < 96)
            frag_cvt_tile(wqkv + (size_t)tile * 16 * 512, oq + (size_t)tile * 8192, t, 1.f);
        else
            frag_cvt_tile(wproj + (size_t)(tile - 96) * 16 * 512,
                          op + (size_t)(tile - 96) * 8192, t, 1.f);
    } else {
        // ---- W1 [256][512] -> W1T [512][256], 64x64 tile per block ----
        __shared__ float tl[64][65];
        const int tile = bid - 384;                // 0..31
        const int tr = tile >> 3, tc = tile & 7;
        const int lr = t >> 6, lc = t & 63;
        #pragma unroll
        for (int p = 0; p < 16; ++p) {
            const int r = p * 4 + lr;
            tl[r][lc] = W1[(size_t)(tr * 64 + r) * 512 + tc * 64 + lc];
        }
        __syncthreads();
        #pragma unroll
        for (int p = 0; p < 16; ++p) {
            const int d = p * 4 + lr;
            w1t[(size_t)(tc * 64 + d) * 256 + tr * 64 + lc] = tl[lc][d];
        }
    }
}

// ============================================================
// QKV GEMM + selector fold — v2 (round-4 proven best): 128x128 block tiles
// (4 waves, 2m x 2n; 64x64 per-wave inner loop, 2-k-step register dbuf) +
// XCD-chunked bijective swizzle. L2-resident panels; latency covered by ILP.
// grid (12, 33): by==32/bx<4 is the selector tail.
// ============================================================
__global__ __launch_bounds__(256)
void gemm_qkv_sel(const unsigned short* __restrict__ xb, const unsigned short* __restrict__ wb,
                  unsigned short* __restrict__ qo, unsigned short* __restrict__ ko,
                  unsigned short* __restrict__ vo,
                  const float* __restrict__ partial, const float* __restrict__ w1t,
                  const float* __restrict__ b1, const float* __restrict__ W2,
                  const float* __restrict__ b2, const float* __restrict__ ltau,
                  float* __restrict__ pwout)
{
    __shared__ __align__(16) unsigned short tile[4][64 * 72];
    const int t = threadIdx.x;
    const int w = t >> 6, l64 = t & 63;

    if (blockIdx.y == 32) {
        if (blockIdx.x >= 4) return;
        const int b = blockIdx.x;
        float* pooled = (float*)&tile[0][0];     // 512 f
        float* hpart  = pooled + 512;            // 4 x 256 f
        float* h1s    = hpart + 1024;            // 256 f
        float* lg     = h1s + 256;               // 3 f
        #pragma unroll
        for (int c = 0; c < 2; ++c) {
            const int col = t + c * 256;
            float s = 0.f;
            for (int p = 0; p < 64; ++p) s += partial[((size_t)b * 64 + p) * 512 + col];
            pooled[col] = s * (1.f / 1024.f);
        }
        __syncthreads();
        {
            // h1 partial: wave w covers pooled-d in [w*128, (w+1)*128)
            float4 acc = make_float4(0.f, 0.f, 0.f, 0.f);
            const float* wt = w1t + (size_t)w * 128 * 256 + l64 * 4;
            for (int d = 0; d < 128; ++d) {
                const float pv = pooled[w * 128 + d];
                float4 wv = *(const float4*)(wt + (size_t)d * 256);
                acc.x += pv * wv.x; acc.y += pv * wv.y;
                acc.z += pv * wv.z; acc.w += pv * wv.w;
            }
            *(float4*)&hpart[w * 256 + l64 * 4] = acc;
        }
        __syncthreads();
        h1s[t] = fmaxf(hpart[t] + hpart[256 + t] + hpart[512 + t] + hpart[768 + t] + b1[t], 0.f);
        __syncthreads();
        if (t < 3) {
            float s = b2[t];
            const float* w2 = W2 + t * 256;
            for (int i = 0; i < 256; ++i) s += w2[i] * h1s[i];
            float tauv = fminf(fmaxf(expf(ltau[0]), 1e-4f), 10.f);
            lg[t] = s / tauv;
        }
        __syncthreads();
        if (t == 0) {
            float m = fmaxf(lg[0], fmaxf(lg[1], lg[2]));
            float e0 = expf(lg[0] - m), e1 = expf(lg[1] - m), e2 = expf(lg[2] - m);
            float inv = 1.f / (e0 + e1 + e2);
            pwout[b * 3 + 0] = e0 * inv;
            pwout[b * 3 + 1] = e1 * inv;
            pwout[b * 3 + 2] = e2 * inv;
        }
        return;
    }

    // ---- GEMM path: XCD-chunked bijective swizzle (384 = 48*8 blocks) ----
    const int wg = blockIdx.y * 12 + blockIdx.x;       // dispatch order, x fastest
    const int sw_id = (wg & 7) * 48 + (wg >> 3);       // XCD k gets logical [k*48, k*48+48)
    const int bx = sw_id % 12, by = sw_id / 12;

    const int ln = l64 & 15, quad = l64 >> 4;
    const int m0  = (by << 7) + ((w >> 1) << 6);       // wave: 64m x 64n quadrant
    const int nb0 = (bx << 7) + ((w & 1) << 6);

    const unsigned short* Abase = xb + ((size_t)(m0 >> 4)) * 8192 + l64 * 8;
    const unsigned short* Bbase = wb + ((size_t)(nb0 >> 4)) * 8192 + l64 * 8;

    floatx4 acc[4][4];
    #pragma unroll
    for (int i = 0; i < 4; ++i)
        #pragma unroll
        for (int j = 0; j < 4; ++j) acc[i][j] = (floatx4){0.f, 0.f, 0.f, 0.f};

    short8 a0[4], b0[4], a1[4], b1v[4];
    #pragma unroll
    for (int i = 0; i < 4; ++i) {
        a0[i] = *(const short8*)(Abase + (size_t)i * 8192);
        b0[i] = *(const short8*)(Bbase + (size_t)i * 8192);
    }
    for (int s = 0; s < 16; s += 2) {
        #pragma unroll
        for (int i = 0; i < 4; ++i) {
            a1[i]  = *(const short8*)(Abase + (size_t)i * 8192 + (s + 1) * 512);
            b1v[i] = *(const short8*)(Bbase + (size_t)i * 8192 + (s + 1) * 512);
        }
        #pragma unroll
        for (int i = 0; i < 4; ++i)
            #pragma unroll
            for (int j = 0; j < 4; ++j)
                acc[i][j] = MFMA16(a0[i], b0[j], acc[i][j]);
        if (s + 2 < 16) {
            #pragma unroll
            for (int i = 0; i < 4; ++i) {
                a0[i] = *(const short8*)(Abase + (size_t)i * 8192 + (s + 2) * 512);
                b0[i] = *(const short8*)(Bbase + (size_t)i * 8192 + (s + 2) * 512);
            }
        }
        #pragma unroll
        for (int i = 0; i < 4; ++i)
            #pragma unroll
            for (int j = 0; j < 4; ++j)
                acc[i][j] = MFMA16(a1[i], b1v[j], acc[i][j]);
    }

    unsigned short* tw = &tile[w][0];
    const int which = nb0 >> 9;                  // 0=q 1=k 2=v
    const int hh = (nb0 >> 6) & 7;
    const int g = (m0 >> 10) * 8 + hh;
    const int lrow0 = m0 & 1023;

    if (which == 2) {
        // reg dimension is contiguous in tw -> pack pairs, store uint2 (b64)
        #pragma unroll
        for (int j = 0; j < 4; ++j)
            #pragma unroll
            for (int i = 0; i < 4; ++i) {
                unsigned u01 = cvt_pk_bf16(acc[i][j][0], acc[i][j][1]);
                unsigned u23 = cvt_pk_bf16(acc[i][j][2], acc[i][j][3]);
                *(uint2*)&tw[(j * 16 + ln) * 72 + i * 16 + quad * 4] = make_uint2(u01, u23);
            }
        const int chunk = lrow0 >> 7;
        const int ks0 = (lrow0 & 127) >> 5;
        unsigned short* dst = vo + (size_t)g * 65536 + (size_t)chunk * 8192;
        #pragma unroll
        for (int et = 0; et < 4; ++et)
            #pragma unroll
            for (int ksl = 0; ksl < 2; ++ksl) {
                const unsigned short* srcp = &tw[(et * 16 + ln) * 72 + ksl * 32 + quad * 8];
                *(short8*)(dst + (et * 4 + ks0 + ksl) * 512 + l64 * 8) = *(const short8*)srcp;
            }
    } else {
        // fold q scale AND log2e (softmax becomes exp2): monotone, radix-safe
        const float sc = (which == 0) ? 0.180336880f : 1.f;   // 0.125 * log2(e)
        #pragma unroll
        for (int j = 0; j < 4; ++j)
            #pragma unroll
            for (int i = 0; i < 4; ++i) {
                unsigned u01 = cvt_pk_bf16(acc[i][j][0] * sc, acc[i][j][1] * sc);
                unsigned u23 = cvt_pk_bf16(acc[i][j][2] * sc, acc[i][j][3] * sc);
                const int rb = (i * 16 + quad * 4) * 72 + j * 16 + ln;
                tw[rb]           = (unsigned short)u01;
                tw[rb + 72]      = (unsigned short)(u01 >> 16);
                tw[rb + 144]     = (unsigned short)u23;
                tw[rb + 216]     = (unsigned short)(u23 >> 16);
            }
        unsigned short* dst = (which == 0 ? qo : ko) + (size_t)g * 65536;
        #pragma unroll
        for (int rt = 0; rt < 4; ++rt)
            #pragma unroll
            for (int eh = 0; eh < 2; ++eh) {
                const unsigned short* srcp = &tw[(rt * 16 + ln) * 72 + eh * 32 + quad * 8];
                *(short8*)(dst + ((size_t)((lrow0 >> 4) + rt)) * 1024 + eh * 512 + l64 * 8) =
                    *(const short8*)srcp;
            }
    }
}

// ============================================================
// Proj GEMM — v2: 64m x 128n per 4-wave block, wave quadrants 32m x 64n;
// grid 256 blocks with XCD-chunked bijective swizzle.
// ============================================================
__global__ __launch_bounds__(256)
void gemm_proj(const unsigned short* __restrict__ ab, const unsigned short* __restrict__ wb,
               const float* __restrict__ bias, float* __restrict__ out)
{
    const int t = threadIdx.x;
    const int w = t >> 6, l64 = t & 63;
    const int ln = l64 & 15, quad = l64 >> 4;

    // grid (4,64) = 256 blocks; swizzle: XCD k gets logical blocks [k*32,(k+1)*32)
    const int wg = blockIdx.y * 4 + blockIdx.x;
    const int sw_id = (wg & 7) * 32 + (wg >> 3);
    const int n0 = ((sw_id & 3) << 7) + ((w & 1) << 6);    // wave: 32m x 64n
    const int m0 = ((sw_id >> 2) << 6) + ((w >> 1) << 5);

    const unsigned short* Abase = ab + ((size_t)(m0 >> 4)) * 8192 + l64 * 8;
    const unsigned short* Bbase = wb + ((size_t)(n0 >> 4)) * 8192 + l64 * 8;

    floatx4 acc[2][4];
    #pragma unroll
    for (int i = 0; i < 2; ++i)
        #pragma unroll
        for (int j = 0; j < 4; ++j) acc[i][j] = (floatx4){0.f, 0.f, 0.f, 0.f};

    short8 a0[2], b0[4], a1[2], b1v[4];
    #pragma unroll
    for (int i = 0; i < 2; ++i) a0[i] = *(const short8*)(Abase + (size_t)i * 8192);
    #pragma unroll
    for (int j = 0; j < 4; ++j) b0[j] = *(const short8*)(Bbase + (size_t)j * 8192);
    for (int s = 0; s < 16; s += 2) {
        #pragma unroll
        for (int i = 0; i < 2; ++i) a1[i]  = *(const short8*)(Abase + (size_t)i * 8192 + (s + 1) * 512);
        #pragma unroll
        for (int j = 0; j < 4; ++j) b1v[j] = *(const short8*)(Bbase + (size_t)j * 8192 + (s + 1) * 512);
        #pragma unroll
        for (int i = 0; i < 2; ++i)
            #pragma unroll
            for (int j = 0; j < 4; ++j)
                acc[i][j] = MFMA16(a0[i], b0[j], acc[i][j]);
        if (s + 2 < 16) {
            #pragma unroll
            for (int i = 0; i < 2; ++i) a0[i] = *(const short8*)(Abase + (size_t)i * 8192 + (s + 2) * 512);
            #pragma unroll
            for (int j = 0; j < 4; ++j) b0[j] = *(const short8*)(Bbase + (size_t)j * 8192 + (s + 2) * 512);
        }
        #pragma unroll
        for (int i = 0; i < 2; ++i)
            #pragma unroll
            for (int j = 0; j < 4; ++j)
                acc[i][j] = MFMA16(a1[i], b1v[j], acc[i][j]);
    }
    #pragma unroll
    for (int j = 0; j < 4; ++j) {
        const float bv = bias[n0 + j * 16 + ln];
        #pragma unroll
        for (int i = 0; i < 2; ++i)
            #pragma unroll
            for (int reg = 0; reg < 4; ++reg)
                out[(size_t)(m0 + i * 16 + quad * 4 + reg) * 512 + n0 + j * 16 + ln] =
                    acc[i][j][reg] + bv;
    }
}

// ============================================================
// Flash attention v6: K dbuf + mid-chunk V drain; exp2 softmax; hw pk cvt;
// s_setprio(1) around MFMA clusters.
// block = 64 Q-rows (wave = 16), grid 512, 2 blocks/CU (LDS 70.9 KB).
// ============================================================
__global__ __launch_bounds__(256)
void attn_flash(const unsigned short* __restrict__ qm, const unsigned short* __restrict__ km,
                const unsigned short* __restrict__ vm, const int* __restrict__ mask,
                const float* __restrict__ pw, const float* __restrict__ sw,
                const float* __restrict__ sb, unsigned short* __restrict__ aout)
{
    __shared__ int mk[1024];
    __shared__ __align__(16) unsigned short Ks[2][8192];   // K chunk double buffer (32 KB)
    __shared__ __align__(16) unsigned short Vs[8192];      // V chunk single buffer (16 KB)
    __shared__ __align__(16) unsigned short Pws[4][2176];  // per-wave P staging [16][136]
    __shared__ unsigned kths[4][16];

    const int t = threadIdx.x;
    const int w = t >> 6, l64 = t & 63;
    const int ln = l64 & 15, quad = l64 >> 4;
    const int g = blockIdx.x & 31;
    const int rg = blockIdx.x >> 5;
    const int b = g >> 3, h = g & 7;
    const int i0 = rg * 64 + w * 16;

    const unsigned short* qg = qm + (size_t)g * 65536;
    const unsigned short* kg = km + (size_t)g * 65536;
    const unsigned short* vg = vm + (size_t)g * 65536;

    *(int4*)&mk[t * 4] = *(const int4*)(mask + b * 1024 + t * 4);

    const float pw0 = pw[b * 3 + 0], pw1 = pw[b * 3 + 1], pw2 = pw[b * 3 + 2];
    const bool a00 = pw1 > 0.05f;
    const bool a10 = (pw0 * 1.0f + pw1) > 0.05f;
    const bool a01 = (pw1 + pw2) > 0.05f;
    const bool a11 = ((pw0 * 1.0f + pw1) + pw2) > 0.05f;
    const bool need_sparse = (!a00 && a01) || (!a10 && a11);
    const bool flat_ok = (!need_sparse) && a00 && a10;  // allowed==true iff mk!=0, exactly
    const float w_h = sw[h], b_h = sb[h];

    // ---- prefetch K chunk 0 -> Ks[0]; drained at the pre-loop barrier ----
    #pragma unroll
    for (int c = 0; c < 4; ++c) {
        const int bi = w * 4 + c;
        gl16(kg + bi * 512 + l64 * 8, (char*)Ks[0] + bi * 1024);
    }

    // ---- rare path: exact per-row kth (k=716), bitwise radix select.
    //      scratch aliases Ks[1] (dead until the pre-loop barrier).
    unsigned kth_r[4] = {0u, 0u, 0u, 0u};
    if (need_sparse) {
        unsigned* ub = (unsigned*)((char*)Ks + 16384 + w * 4096);
        for (int r = 0; r < 16; ++r) {
            for (int c = 0; c < 16; ++c) {
                const int col = c * 64 + l64;
                float s = 0.f;
                for (int e = 0; e < 64; ++e)
                    s += bf2f(qg[FRAGQK(i0 + r, e)]) * bf2f(kg[FRAGQK(col, e)]);
                unsigned uu = __float_as_uint(s * w_h + b_h);
                ub[col] = (uu & 0x80000000u) ? ~uu : (uu | 0x80000000u);
            }
            unsigned u[16];
            #pragma unroll
            for (int c = 0; c < 16; ++c) u[c] = ub[l64 + c * 64];
            unsigned act = 0xFFFFu, p = 0u;
            int kk = 716;
            for (int bit = 31; bit >= 0; --bit) {
                unsigned ones = 0u;
                #pragma unroll
                for (int c = 0; c < 16; ++c)
                    if (((act >> c) & 1u) && ((u[c] >> bit) & 1u)) ones |= (1u << c);
                int c1 = __popc(ones);
                for (int off = 32; off; off >>= 1) c1 += __shfl_xor(c1, off);
                if (kk <= c1) { p |= (1u << bit); act &= ones; }
                else          { kk -= c1; act &= ~ones; }
            }
            if (l64 == 0) kths[w][r] = p;
        }
        #pragma unroll
        for (int reg = 0; reg < 4; ++reg) kth_r[reg] = kths[w][quad * 4 + reg];
    }

    const short8 aq0 = *(const short8*)(qg + ((size_t)(i0 >> 4)) * 1024 + l64 * 8);
    const short8 aq1 = *(const short8*)(qg + ((size_t)(i0 >> 4)) * 1024 + 512 + l64 * 8);

    __syncthreads();   // K(0) landed; mk visible; radix scratch in Ks[1] dead

    float l_acc[4] = {0.f, 0.f, 0.f, 0.f};     // per-lane partial row sums
    floatx4 accv[4];
    #pragma unroll
    for (int et = 0; et < 4; ++et) accv[et] = (floatx4){0.f, 0.f, 0.f, 0.f};
    unsigned short* Pw = &Pws[w][0];

    for (int jc = 0; jc < 8; ++jc) {
        const int j0 = jc << 7;
        const int cur = jc & 1;
        const unsigned short* Kc = &Ks[cur][0];
        // ---- stage V(jc) now (consumed after the MID barrier);
        //      prefetch K(jc+1) into the spare K buffer (consumed next chunk) ----
        {
            const unsigned short* vc = vg + (size_t)jc * 8192;
            #pragma unroll
            for (int c = 0; c < 4; ++c) {
                const int bi = w * 4 + c;
                gl16(vc + bi * 512 + l64 * 8, (char*)Vs + bi * 1024);
            }
            if (jc < 7) {
                const unsigned short* kc = kg + (size_t)(jc + 1) * 8192;
                #pragma unroll
                for (int c = 0; c < 4; ++c) {
                    const int bi = w * 4 + c;
                    gl16(kc + bi * 512 + l64 * 8, (char*)Ks[cur ^ 1] + bi * 1024);
                }
            }
        }
        const bool mall = __all((mk[j0 + l64] != 0) && (mk[j0 + 64 + l64] != 0));
        const bool fast = flat_ok && mall;

        // ---- QK^T from LDS K (K(jc) landed at the previous barrier) ----
        floatx4 sfr[8];
        __builtin_amdgcn_s_setprio(1);
        #pragma unroll
        for (int nt = 0; nt < 8; ++nt) {
            const short8 kb0 = *(const short8*)(Kc + nt * 1024 + l64 * 8);
            const short8 kb1 = *(const short8*)(Kc + nt * 1024 + 512 + l64 * 8);
            floatx4 z = (floatx4){0.f, 0.f, 0.f, 0.f};
            z = MFMA16(aq0, kb0, z);
            z = MFMA16(aq1, kb1, z);
            sfr[nt] = z;
        }
        __builtin_amdgcn_s_setprio(0);

        // ---- masking (no row-max needed: m fixed at 0) ----
        if (!fast) {
            #pragma unroll
            for (int nt = 0; nt < 8; ++nt) {
                const int j = j0 + nt * 16 + ln;
                const bool mk0 = (mk[j] == 0);
                #pragma unroll
                for (int reg = 0; reg < 4; ++reg) {
                    const int i = i0 + quad * 4 + reg;
                    const float s = sfr[nt][reg];
                    const bool loc = (j >= i - 16) && (j <= i + 16);
                    bool sm = false;
                    if (need_sparse) {
                        unsigned uu = __float_as_uint(s * w_h + b_h);
                        unsigned key = (uu & 0x80000000u) ? ~uu : (uu | 0x80000000u);
                        sm = key >= kth_r[reg];
                    }
                    bool allowed = loc ? (sm ? a11 : a10) : (sm ? a01 : a00);
                    if (mk0) allowed = false;
                    sfr[nt][reg] = allowed ? s : -1e9f;
                }
            }
        }
        // ---- P = exp2(s) -> bf16 (hw pk cvt) -> wave-private LDS ----
        #pragma unroll
        for (int nt = 0; nt < 8; ++nt) {
            const float p0 = __ocml_native_exp2_f32(sfr[nt][0]);  // masked -> +0 exactly
            const float p1 = __ocml_native_exp2_f32(sfr[nt][1]);
            const float p2 = __ocml_native_exp2_f32(sfr[nt][2]);
            const float p3 = __ocml_native_exp2_f32(sfr[nt][3]);
            l_acc[0] += p0; l_acc[1] += p1; l_acc[2] += p2; l_acc[3] += p3;
            const unsigned u01 = cvt_pk_bf16(p0, p1);
            const unsigned u23 = cvt_pk_bf16(p2, p3);
            const int col = nt * 16 + ln;
            Pw[(quad * 4 + 0) * 136 + col] = (unsigned short)u01;
            Pw[(quad * 4 + 1) * 136 + col] = (unsigned short)(u01 >> 16);
            Pw[(quad * 4 + 2) * 136 + col] = (unsigned short)u23;
            Pw[(quad * 4 + 3) * 136 + col] = (unsigned short)(u23 >> 16);
        }
        short8 pa[4];
        #pragma unroll
        for (int ks = 0; ks < 4; ++ks)
            pa[ks] = *(const short8*)&Pw[ln * 136 + ks * 32 + quad * 8];
        __syncthreads();   // MID: drains V(jc)+K(jc+1) under the QK^T/exp shadow
        // ---- PV from LDS V (no alpha rescale: m is constant) ----
        __builtin_amdgcn_s_setprio(1);
        #pragma unroll
        for (int et = 0; et < 4; ++et) {
            floatx4 a = accv[et];
            #pragma unroll
            for (int ks = 0; ks < 4; ++ks) {
                const short8 bv = *(const short8*)(Vs + (et * 4 + ks) * 512 + l64 * 8);
                a = MFMA16(pa[ks], bv, a);
            }
            accv[et] = a;
        }
        __builtin_amdgcn_s_setprio(0);
        __syncthreads();   // END: Vs consumed -> next chunk may restage it
    }

    // ---- single deferred row-sum reduce (16 shuffles total) ----
    #pragma unroll
    for (int reg = 0; reg < 4; ++reg) {
        float v = l_acc[reg];
        v += __shfl_xor(v, 1);
        v += __shfl_xor(v, 2);
        v += __shfl_xor(v, 4);
        v += __shfl_xor(v, 8);
        l_acc[reg] = v;
    }

    // ---- writeback: normalize (or exact v[0] fallback when l==0).
    //      fp32 staging aliases the now-dead Ks buffer ([16][68] per wave). ----
    float* PO_w = (float*)((char*)Ks + w * 4352);
    #pragma unroll
    for (int et = 0; et < 4; ++et)
        #pragma unroll
        for (int reg = 0; reg < 4; ++reg) {
            float val;
            if (l_acc[reg] == 0.f)
                val = bf2f(vg[et * 2048 + ln * 8]);   // v[0][e], e = et*16+ln
            else
                val = accv[et][reg] / l_acc[reg];
            PO_w[(quad * 4 + reg) * 68 + et * 16 + ln] = val;
        }
    #pragma unroll
    for (int rr = 0; rr < 4; ++rr) {
        const int r = (l64 >> 4) * 4 + rr;
        const int cb = (l64 & 15) * 4;
        float4 ov = *(const float4*)&PO_w[r * 68 + cb];
        const unsigned uxy = cvt_pk_bf16(ov.x, ov.y);
        const unsigned uzw = cvt_pk_bf16(ov.z, ov.w);
        const int row_g = b * 1024 + i0 + r;
        const int col = h * 64 + cb;
        *(uint2*)&aout[FRAG512(row_g, col)] = make_uint2(uxy, uzw);
    }
}

// ============================================================
extern "C" void kernel_launch(void* const* d_in, const int* in_sizes, int n_in,
                              void* d_out, int out_size, void* d_ws, size_t ws_size,
                              hipStream_t stream) {
    const float* x     = (const float*)d_in[0];
    const int*   mask  = (const int*)d_in[1];
    const float* Wqkv  = (const float*)d_in[2];
    const float* Wproj = (const float*)d_in[3];
    const float* bproj = (const float*)d_in[4];
    const float* Wsel1 = (const float*)d_in[5];
    const float* bsel1 = (const float*)d_in[6];
    const float* Wsel2 = (const float*)d_in[7];
    const float* bsel2 = (const float*)d_in[8];
    const float* ltau  = (const float*)d_in[9];
    const float* sw    = (const float*)d_in[10];
    const float* sb    = (const float*)d_in[11];
    char* ws = (char*)d_ws;
    unsigned short* xb     = (unsigned short*)(ws + OFF_XB);
    unsigned short* wqkvb  = (unsigned short*)(ws + OFF_WQKV);
    unsigned short* wprojb = (unsigned short*)(ws + OFF_WPROJ);
    unsigned short* q      = (unsigned short*)(ws + OFF_Q);
    unsigned short* k      = (unsigned short*)(ws + OFF_K);
    unsigned short* v      = (unsigned short*)(ws + OFF_VT);
    unsigned short* attnb  = (unsigned short*)(ws + OFF_AT);
    float* pw  = (float*)(ws + OFF_PW);
    float* par = (float*)(ws + OFF_PAR);
    float* w1t = (float*)(ws + OFF_W1T);
    float* out = (float*)d_out;
    (void)in_sizes; (void)n_in; (void)out_size; (void)ws_size;

    cvt_all<<<416, 256, 0, stream>>>(x, Wqkv, Wproj, Wsel1, xb, wqkvb, wprojb, par, w1t);
    gemm_qkv_sel<<<dim3(12, 33), 256, 0, stream>>>(xb, wqkvb, q, k, v,
                                                   par, w1t, bsel1, Wsel2, bsel2, ltau, pw);
    attn_flash<<<512, 256, 0, stream>>>(q, k, v, mask, pw, sw, sb, attnb);
    gemm_proj<<<dim3(4, 64), 256, 0, stream>>>(attnb, wprojb, bproj, out);
}